// Round 1
// baseline (2393.749 us; speedup 1.0000x reference)
//
#include <hip/hip_runtime.h>
#include <hip/hip_bf16.h>
#include <math.h>

// MoE: B=4,S=2048 -> T=8192 tokens, D=2048, E=8 experts, F=2048, top-2.
#define T_TOK 8192
#define DDIM  2048
#define NEXP  8
#define FDIM  2048

typedef __bf16 bf16x8 __attribute__((ext_vector_type(8)));
typedef float  f32x4  __attribute__((ext_vector_type(4)));

#define MFMA16(a, b, c) __builtin_amdgcn_mfma_f32_16x16x32_bf16((a), (b), (c), 0, 0, 0)

__device__ __forceinline__ unsigned short f2bf(float f) {
  // round-to-nearest-even fp32 -> bf16 bits
  unsigned int u = __builtin_bit_cast(unsigned int, f);
  u += 0x7fffu + ((u >> 16) & 1u);
  return (unsigned short)(u >> 16);
}

// ---------------- router: logits -> softmax -> top2 ----------------
__global__ __launch_bounds__(256) void k_router(
    const float* __restrict__ x, const float* __restrict__ gw,
    int* __restrict__ cnt, int* __restrict__ topk_e, float* __restrict__ topk_w) {
  int lane = threadIdx.x & 63;
  int wave = threadIdx.x >> 6;
  int t = blockIdx.x * 4 + wave;
  const float* xr = x + (size_t)t * DDIM;
  float acc[NEXP];
#pragma unroll
  for (int e = 0; e < NEXP; e++) acc[e] = 0.f;
  for (int j = lane; j < DDIM; j += 64) {
    float xv = xr[j];
#pragma unroll
    for (int e = 0; e < NEXP; e++) acc[e] += xv * gw[e * DDIM + j];
  }
#pragma unroll
  for (int e = 0; e < NEXP; e++) {
    for (int off = 32; off > 0; off >>= 1) acc[e] += __shfl_down(acc[e], off, 64);
  }
  if (lane == 0) {
    float m = acc[0];
#pragma unroll
    for (int e = 1; e < NEXP; e++) m = fmaxf(m, acc[e]);
    float p[NEXP];
    float s = 0.f;
#pragma unroll
    for (int e = 0; e < NEXP; e++) { p[e] = expf(acc[e] - m); s += p[e]; }
    float inv = 1.f / s;
    int e1 = 0; float v1 = p[0];
#pragma unroll
    for (int e = 1; e < NEXP; e++) if (p[e] > v1) { v1 = p[e]; e1 = e; }
    int e2 = -1; float v2 = -1.f;
#pragma unroll
    for (int e = 0; e < NEXP; e++) {
      if (e == e1) continue;
      if (p[e] > v2) { v2 = p[e]; e2 = e; }
    }
    topk_e[t * 2 + 0] = e1; topk_w[t * 2 + 0] = v1 * inv;
    topk_e[t * 2 + 1] = e2; topk_w[t * 2 + 1] = v2 * inv;
    atomicAdd(&cnt[e1], 1);
    atomicAdd(&cnt[e2], 1);
  }
}

__global__ void k_scan(const int* __restrict__ cnt, int* __restrict__ prefix) {
  if (threadIdx.x == 0 && blockIdx.x == 0) {
    int s = 0;
    for (int e = 0; e < NEXP; e++) { prefix[e] = s; s += cnt[e]; }
    prefix[NEXP] = s;
  }
}

__global__ __launch_bounds__(256) void k_assign(
    const int* __restrict__ topk_e, const float* __restrict__ topk_w,
    const int* __restrict__ prefix, int* __restrict__ fill,
    int* __restrict__ toks, float* __restrict__ rwc) {
  int t = blockIdx.x * 256 + threadIdx.x;
  if (t >= T_TOK) return;
#pragma unroll
  for (int k = 0; k < 2; k++) {
    int e = topk_e[t * 2 + k];
    float w = topk_w[t * 2 + k];
    int pos = atomicAdd(&fill[e], 1);
    int slot = prefix[e] + pos;
    toks[slot] = t;
    rwc[slot] = w;
  }
}

// ---------------- GEMM1: H = silu(X W1^T) * (X W3^T), bf16 out ----------------
#define BM 64
#define BN 64
#define BK 32
#define LSTR 40  // lds row stride in elements (pad 32 -> 40: 2-way bank alias = free)

__global__ __launch_bounds__(256) void k_gemm1(
    const float* __restrict__ x, const float* __restrict__ w1,
    const float* __restrict__ w3, const int* __restrict__ cnt,
    const int* __restrict__ prefix, const int* __restrict__ toks,
    unsigned short* __restrict__ hbuf) {
  int e  = blockIdx.x >> 7;   // / 128 m-blocks per expert (worst case T/64)
  int mb = blockIdx.x & 127;
  int ne = cnt[e];
  if (mb * BM >= ne) return;
  int base = prefix[e];
  int fb = blockIdx.y;  // F/64

  __shared__ __align__(16) unsigned short As[BM][LSTR];
  __shared__ __align__(16) unsigned short B1s[BN][LSTR];
  __shared__ __align__(16) unsigned short B3s[BN][LSTR];
  __shared__ int ltok[BM];

  int tid = threadIdx.x;
  if (tid < BM) {
    int i = mb * BM + tid;
    ltok[tid] = (i < ne) ? toks[base + i] : -1;
  }
  __syncthreads();

  int lane = tid & 63;
  int wv = tid >> 6;
  int wm = (wv >> 1) * 32;
  int wn = (wv & 1) * 32;

  f32x4 accG[2][2], accU[2][2];
#pragma unroll
  for (int i = 0; i < 2; i++)
#pragma unroll
    for (int j = 0; j < 2; j++) { accG[i][j] = (f32x4){0,0,0,0}; accU[i][j] = (f32x4){0,0,0,0}; }

  int sr = tid >> 2;         // staging row 0..63
  int sk = (tid & 3) * 8;    // staging k offset 0,8,16,24
  int tok = ltok[sr];
  const float* aSrc  = x + ((tok >= 0) ? ((size_t)tok * DDIM + sk) : 0);
  const float* b1Src = w1 + ((size_t)e * FDIM + (size_t)fb * BN + sr) * DDIM + sk;
  const float* b3Src = w3 + ((size_t)e * FDIM + (size_t)fb * BN + sr) * DDIM + sk;

  int fr = lane & 15;
  int q  = lane >> 4;

  for (int k0 = 0; k0 < DDIM; k0 += BK) {
    // stage A (gathered token rows, fp32 -> bf16)
    {
      union { unsigned short u[8]; int4 v; } pk;
      if (tok >= 0) {
        float4 f0 = *(const float4*)(aSrc + k0);
        float4 f1 = *(const float4*)(aSrc + k0 + 4);
        pk.u[0] = f2bf(f0.x); pk.u[1] = f2bf(f0.y); pk.u[2] = f2bf(f0.z); pk.u[3] = f2bf(f0.w);
        pk.u[4] = f2bf(f1.x); pk.u[5] = f2bf(f1.y); pk.u[6] = f2bf(f1.z); pk.u[7] = f2bf(f1.w);
      } else {
        pk.v = (int4){0, 0, 0, 0};
      }
      *(int4*)(&As[sr][sk]) = pk.v;
    }
    {
      union { unsigned short u[8]; int4 v; } pk;
      float4 f0 = *(const float4*)(b1Src + k0);
      float4 f1 = *(const float4*)(b1Src + k0 + 4);
      pk.u[0] = f2bf(f0.x); pk.u[1] = f2bf(f0.y); pk.u[2] = f2bf(f0.z); pk.u[3] = f2bf(f0.w);
      pk.u[4] = f2bf(f1.x); pk.u[5] = f2bf(f1.y); pk.u[6] = f2bf(f1.z); pk.u[7] = f2bf(f1.w);
      *(int4*)(&B1s[sr][sk]) = pk.v;
    }
    {
      union { unsigned short u[8]; int4 v; } pk;
      float4 f0 = *(const float4*)(b3Src + k0);
      float4 f1 = *(const float4*)(b3Src + k0 + 4);
      pk.u[0] = f2bf(f0.x); pk.u[1] = f2bf(f0.y); pk.u[2] = f2bf(f0.z); pk.u[3] = f2bf(f0.w);
      pk.u[4] = f2bf(f1.x); pk.u[5] = f2bf(f1.y); pk.u[6] = f2bf(f1.z); pk.u[7] = f2bf(f1.w);
      *(int4*)(&B3s[sr][sk]) = pk.v;
    }
    __syncthreads();

    bf16x8 af[2], b1f[2], b3f[2];
#pragma unroll
    for (int sm = 0; sm < 2; sm++) af[sm] = *(const bf16x8*)(&As[wm + sm * 16 + fr][q * 8]);
#pragma unroll
    for (int sn = 0; sn < 2; sn++) {
      b1f[sn] = *(const bf16x8*)(&B1s[wn + sn * 16 + fr][q * 8]);
      b3f[sn] = *(const bf16x8*)(&B3s[wn + sn * 16 + fr][q * 8]);
    }
#pragma unroll
    for (int sm = 0; sm < 2; sm++)
#pragma unroll
      for (int sn = 0; sn < 2; sn++) {
        accG[sm][sn] = MFMA16(af[sm], b1f[sn], accG[sm][sn]);
        accU[sm][sn] = MFMA16(af[sm], b3f[sn], accU[sm][sn]);
      }
    __syncthreads();
  }

  // epilogue: silu(G)*U -> bf16 hbuf (compact per-assignment rows)
#pragma unroll
  for (int sm = 0; sm < 2; sm++) {
#pragma unroll
    for (int sn = 0; sn < 2; sn++) {
#pragma unroll
      for (int r = 0; r < 4; r++) {
        int row = mb * BM + wm + sm * 16 + q * 4 + r;
        if (row < ne) {
          int col = fb * BN + wn + sn * 16 + fr;
          float g = accG[sm][sn][r];
          float u = accU[sm][sn][r];
          float h = (g / (1.f + expf(-g))) * u;
          hbuf[(size_t)(base + row) * FDIM + col] = f2bf(h);
        }
      }
    }
  }
}

// ---------------- GEMM2: Y += rw * (H W2^T), atomic scatter into y ----------------
__global__ __launch_bounds__(256) void k_gemm2(
    const unsigned short* __restrict__ hbuf, const float* __restrict__ w2,
    const int* __restrict__ cnt, const int* __restrict__ prefix,
    const int* __restrict__ toks, const float* __restrict__ rwc,
    float* __restrict__ y) {
  int e  = blockIdx.x >> 7;
  int mb = blockIdx.x & 127;
  int ne = cnt[e];
  if (mb * BM >= ne) return;
  int base = prefix[e];
  int db = blockIdx.y;  // D/64

  __shared__ __align__(16) unsigned short As[BM][LSTR];
  __shared__ __align__(16) unsigned short Bs[BN][LSTR];
  __shared__ int ltok[BM];
  __shared__ float lrw[BM];

  int tid = threadIdx.x;
  if (tid < BM) {
    int i = mb * BM + tid;
    ltok[tid] = (i < ne) ? toks[base + i] : -1;
    lrw[tid]  = (i < ne) ? rwc[base + i] : 0.f;
  }
  __syncthreads();

  int lane = tid & 63;
  int wv = tid >> 6;
  int wm = (wv >> 1) * 32;
  int wn = (wv & 1) * 32;

  f32x4 acc[2][2];
#pragma unroll
  for (int i = 0; i < 2; i++)
#pragma unroll
    for (int j = 0; j < 2; j++) acc[i][j] = (f32x4){0,0,0,0};

  int sr = tid >> 2;
  int sk = (tid & 3) * 8;
  int rowA = mb * BM + sr;
  bool aValid = rowA < ne;
  const unsigned short* aSrc = hbuf + (size_t)(base + rowA) * FDIM + sk;
  const float* bSrc = w2 + ((size_t)e * DDIM + (size_t)db * BN + sr) * FDIM + sk;

  int fr = lane & 15;
  int q  = lane >> 4;

  for (int k0 = 0; k0 < FDIM; k0 += BK) {
    if (aValid) {
      *(int4*)(&As[sr][sk]) = *(const int4*)(aSrc + k0);
    } else {
      *(int4*)(&As[sr][sk]) = (int4){0, 0, 0, 0};
    }
    {
      union { unsigned short u[8]; int4 v; } pk;
      float4 f0 = *(const float4*)(bSrc + k0);
      float4 f1 = *(const float4*)(bSrc + k0 + 4);
      pk.u[0] = f2bf(f0.x); pk.u[1] = f2bf(f0.y); pk.u[2] = f2bf(f0.z); pk.u[3] = f2bf(f0.w);
      pk.u[4] = f2bf(f1.x); pk.u[5] = f2bf(f1.y); pk.u[6] = f2bf(f1.z); pk.u[7] = f2bf(f1.w);
      *(int4*)(&Bs[sr][sk]) = pk.v;
    }
    __syncthreads();

    bf16x8 af[2], bf[2];
#pragma unroll
    for (int sm = 0; sm < 2; sm++) af[sm] = *(const bf16x8*)(&As[wm + sm * 16 + fr][q * 8]);
#pragma unroll
    for (int sn = 0; sn < 2; sn++) bf[sn] = *(const bf16x8*)(&Bs[wn + sn * 16 + fr][q * 8]);
#pragma unroll
    for (int sm = 0; sm < 2; sm++)
#pragma unroll
      for (int sn = 0; sn < 2; sn++) acc[sm][sn] = MFMA16(af[sm], bf[sn], acc[sm][sn]);
    __syncthreads();
  }

#pragma unroll
  for (int sm = 0; sm < 2; sm++) {
#pragma unroll
    for (int sn = 0; sn < 2; sn++) {
#pragma unroll
      for (int r = 0; r < 4; r++) {
        int lrow = wm + sm * 16 + q * 4 + r;
        int row = mb * BM + lrow;
        if (row < ne) {
          int tok = ltok[lrow];
          float w = lrw[lrow];
          int col = db * BN + wn + sn * 16 + fr;
          atomicAdd(&y[(size_t)tok * DDIM + col], acc[sm][sn][r] * w);
        }
      }
    }
  }
}

// ---------------- launch ----------------
// ws layout (bytes):
//   0      : cnt[8]
//   256    : fill[8]
//   512    : prefix[9]
//   1024   : topk_e[T*2]  (64 KiB)
//   66560  : topk_w[T*2]  (64 KiB)
//   132096 : toks[T*2]    (64 KiB)
//   197632 : rwc[T*2]     (64 KiB)
//   263168 : hbuf[T*2][F] bf16 (64 MiB)  -> total ~67.4 MB
extern "C" void kernel_launch(void* const* d_in, const int* in_sizes, int n_in,
                              void* d_out, int out_size, void* d_ws, size_t ws_size,
                              hipStream_t stream) {
  const float* x  = (const float*)d_in[0];
  const float* gw = (const float*)d_in[1];
  const float* w1 = (const float*)d_in[2];
  const float* w3 = (const float*)d_in[3];
  const float* w2 = (const float*)d_in[4];
  float* y = (float*)d_out;

  char* ws = (char*)d_ws;
  int*   cnt    = (int*)(ws + 0);
  int*   fill   = (int*)(ws + 256);
  int*   prefix = (int*)(ws + 512);
  int*   topk_e = (int*)(ws + 1024);
  float* topk_w = (float*)(ws + 66560);
  int*   toks   = (int*)(ws + 132096);
  float* rwc    = (float*)(ws + 197632);
  unsigned short* hbuf = (unsigned short*)(ws + 263168);

  hipMemsetAsync(ws, 0, 1024, stream);                                  // cnt/fill/prefix
  hipMemsetAsync(d_out, 0, (size_t)out_size * sizeof(float), stream);   // y = 0

  k_router<<<T_TOK / 4, 256, 0, stream>>>(x, gw, cnt, topk_e, topk_w);
  k_scan<<<1, 64, 0, stream>>>(cnt, prefix);
  k_assign<<<T_TOK / 256, 256, 0, stream>>>(topk_e, topk_w, prefix, fill, toks, rwc);
  k_gemm1<<<dim3(NEXP * 128, FDIM / BN), 256, 0, stream>>>(x, w1, w3, cnt, prefix, toks, hbuf);
  k_gemm2<<<dim3(NEXP * 128, DDIM / BN), 256, 0, stream>>>(hbuf, w2, cnt, prefix, toks, rwc, y);
}

// Round 2
// 1792.314 us; speedup vs baseline: 1.3356x; 1.3356x over previous
//
#include <hip/hip_runtime.h>
#include <hip/hip_bf16.h>
#include <math.h>

// MoE: B=4,S=2048 -> T=8192 tokens, D=2048, E=8 experts, F=2048, top-2.
#define T_TOK 8192
#define DDIM  2048
#define NEXP  8
#define FDIM  2048
#define BK    32

typedef __bf16 bf16x8 __attribute__((ext_vector_type(8)));
typedef float  f32x4  __attribute__((ext_vector_type(4)));

#define MFMA16(a, b, c) __builtin_amdgcn_mfma_f32_16x16x32_bf16((a), (b), (c), 0, 0, 0)

// async global->LDS, 16B per lane; LDS dest = wave-uniform base + lane*16
#define GLDS16(g, l)                                                            \
  __builtin_amdgcn_global_load_lds(                                             \
      (const __attribute__((address_space(1))) void*)(g),                       \
      (__attribute__((address_space(3))) void*)(l), 16, 0, 0)

__device__ __forceinline__ unsigned short f2bf(float f) {
  unsigned int u = __builtin_bit_cast(unsigned int, f);
  u += 0x7fffu + ((u >> 16) & 1u);
  return (unsigned short)(u >> 16);
}

// ---------------- fp32 -> bf16 bulk convert (8 elems/thread, grid-stride) ----
__global__ __launch_bounds__(256) void k_cvt(const float* __restrict__ src,
                                             unsigned short* __restrict__ dst,
                                             long n) {
  long i = ((long)blockIdx.x * 256 + threadIdx.x) * 8;
  long stride = (long)gridDim.x * 256 * 8;
  for (; i < n; i += stride) {
    float4 f0 = *(const float4*)(src + i);
    float4 f1 = *(const float4*)(src + i + 4);
    union { unsigned short u[8]; int4 v; } pk;
    pk.u[0] = f2bf(f0.x); pk.u[1] = f2bf(f0.y); pk.u[2] = f2bf(f0.z); pk.u[3] = f2bf(f0.w);
    pk.u[4] = f2bf(f1.x); pk.u[5] = f2bf(f1.y); pk.u[6] = f2bf(f1.z); pk.u[7] = f2bf(f1.w);
    *(int4*)(dst + i) = pk.v;
  }
}

// ---------------- router: fp32 logits -> softmax -> top2 ----------------
__global__ __launch_bounds__(256) void k_router(
    const float* __restrict__ x, const float* __restrict__ gw,
    int* __restrict__ cnt, int* __restrict__ topk_e, float* __restrict__ topk_w) {
  int lane = threadIdx.x & 63;
  int wave = threadIdx.x >> 6;
  int t = blockIdx.x * 4 + wave;
  const float* xr = x + (size_t)t * DDIM;
  float acc[NEXP];
#pragma unroll
  for (int e = 0; e < NEXP; e++) acc[e] = 0.f;
  for (int j = lane; j < DDIM; j += 64) {
    float xv = xr[j];
#pragma unroll
    for (int e = 0; e < NEXP; e++) acc[e] += xv * gw[e * DDIM + j];
  }
#pragma unroll
  for (int e = 0; e < NEXP; e++) {
    for (int off = 32; off > 0; off >>= 1) acc[e] += __shfl_down(acc[e], off, 64);
  }
  if (lane == 0) {
    float m = acc[0];
#pragma unroll
    for (int e = 1; e < NEXP; e++) m = fmaxf(m, acc[e]);
    float p[NEXP]; float s = 0.f;
#pragma unroll
    for (int e = 0; e < NEXP; e++) { p[e] = expf(acc[e] - m); s += p[e]; }
    float inv = 1.f / s;
    int e1 = 0; float v1 = p[0];
#pragma unroll
    for (int e = 1; e < NEXP; e++) if (p[e] > v1) { v1 = p[e]; e1 = e; }
    int e2 = -1; float v2 = -1.f;
#pragma unroll
    for (int e = 0; e < NEXP; e++) {
      if (e == e1) continue;
      if (p[e] > v2) { v2 = p[e]; e2 = e; }
    }
    topk_e[t * 2 + 0] = e1; topk_w[t * 2 + 0] = v1 * inv;
    topk_e[t * 2 + 1] = e2; topk_w[t * 2 + 1] = v2 * inv;
    atomicAdd(&cnt[e1], 1);
    atomicAdd(&cnt[e2], 1);
  }
}

__global__ void k_scan(const int* __restrict__ cnt, int* __restrict__ prefix) {
  if (threadIdx.x == 0 && blockIdx.x == 0) {
    int s = 0;
    for (int e = 0; e < NEXP; e++) { prefix[e] = s; s += cnt[e]; }
    prefix[NEXP] = s;
  }
}

__global__ __launch_bounds__(256) void k_assign(
    const int* __restrict__ topk_e, const float* __restrict__ topk_w,
    const int* __restrict__ prefix, int* __restrict__ fill,
    int* __restrict__ toks, float* __restrict__ rwc) {
  int t = blockIdx.x * 256 + threadIdx.x;
  if (t >= T_TOK) return;
#pragma unroll
  for (int k = 0; k < 2; k++) {
    int e = topk_e[t * 2 + k];
    float w = topk_w[t * 2 + k];
    int pos = atomicAdd(&fill[e], 1);
    int slot = prefix[e] + pos;
    toks[slot] = t;
    rwc[slot] = w;
  }
}

// ---------------- GEMM1: H = silu(X W1^T) * (X W3^T), 128x64 tile ------------
// A = gathered token rows (bf16), B1/B3 = w1/w3 rows (bf16). global_load_lds
// staging, unpadded LDS [row][32] (m97 recipe). Dual accumulators share A-frags.
__global__ __launch_bounds__(256) void k_gemm1(
    const unsigned short* __restrict__ xb, const unsigned short* __restrict__ w1b,
    const unsigned short* __restrict__ w3b, const int* __restrict__ cnt,
    const int* __restrict__ prefix, const int* __restrict__ toks,
    unsigned short* __restrict__ hbuf) {
  int e  = blockIdx.x >> 6;   // 64 m-blocks per expert (worst case 8192/128)
  int mb = blockIdx.x & 63;
  int ne = cnt[e];
  if (mb * 128 >= ne) return;
  int base = prefix[e];
  int fb = blockIdx.y;        // F/64

  __shared__ __align__(16) unsigned short As[128 * BK];
  __shared__ __align__(16) unsigned short B1s[64 * BK];
  __shared__ __align__(16) unsigned short B3s[64 * BK];
  __shared__ int ltok[128];

  int tid = threadIdx.x;
  if (tid < 128) {
    int i = mb * 128 + tid;
    ltok[tid] = (i < ne) ? toks[base + i] : 0;  // pad rows read token 0 (masked at store)
  }
  __syncthreads();

  int lane = tid & 63;
  int wv = tid >> 6;

  // staging: 16 segments of 16 rows x 64B. waves 0,1 -> A; wave 2 -> B1; wave 3 -> B3.
  int r_in_seg = lane >> 2;       // 0..15
  int c16 = (lane & 3) * 8;       // bf16 col offset 0,8,16,24
  const unsigned short* gsrc[4];
  unsigned short* ldst[4];
#pragma unroll
  for (int i = 0; i < 4; i++) {
    if (wv < 2) {
      int row = (wv * 4 + i) * 16 + r_in_seg;   // 0..127
      gsrc[i] = xb + (size_t)ltok[row] * DDIM + c16;
      ldst[i] = (unsigned short*)As + (wv * 4 + i) * 16 * BK;
    } else if (wv == 2) {
      int row = i * 16 + r_in_seg;              // 0..63
      gsrc[i] = w1b + ((size_t)e * FDIM + fb * 64 + row) * DDIM + c16;
      ldst[i] = (unsigned short*)B1s + i * 16 * BK;
    } else {
      int row = i * 16 + r_in_seg;
      gsrc[i] = w3b + ((size_t)e * FDIM + fb * 64 + row) * DDIM + c16;
      ldst[i] = (unsigned short*)B3s + i * 16 * BK;
    }
  }

  int fr = lane & 15;
  int q  = lane >> 4;
  int wm = (wv >> 1) * 64;   // wave grid 2x2: {0,64} x {0,32}
  int wn = (wv & 1) * 32;

  f32x4 accG[4][2], accU[4][2];
#pragma unroll
  for (int i = 0; i < 4; i++)
#pragma unroll
    for (int j = 0; j < 2; j++) { accG[i][j] = (f32x4){0,0,0,0}; accU[i][j] = (f32x4){0,0,0,0}; }

  for (int k0 = 0; k0 < DDIM; k0 += BK) {
#pragma unroll
    for (int i = 0; i < 4; i++) GLDS16(gsrc[i] + k0, ldst[i]);
    __syncthreads();

    bf16x8 af[4], b1f[2], b3f[2];
#pragma unroll
    for (int sm = 0; sm < 4; sm++)
      af[sm] = *(const bf16x8*)(As + (wm + sm * 16 + fr) * BK + q * 8);
#pragma unroll
    for (int sn = 0; sn < 2; sn++) {
      b1f[sn] = *(const bf16x8*)(B1s + (wn + sn * 16 + fr) * BK + q * 8);
      b3f[sn] = *(const bf16x8*)(B3s + (wn + sn * 16 + fr) * BK + q * 8);
    }
#pragma unroll
    for (int sm = 0; sm < 4; sm++)
#pragma unroll
      for (int sn = 0; sn < 2; sn++) {
        accG[sm][sn] = MFMA16(af[sm], b1f[sn], accG[sm][sn]);
        accU[sm][sn] = MFMA16(af[sm], b3f[sn], accU[sm][sn]);
      }
    __syncthreads();
  }

#pragma unroll
  for (int sm = 0; sm < 4; sm++)
#pragma unroll
    for (int sn = 0; sn < 2; sn++)
#pragma unroll
      for (int r = 0; r < 4; r++) {
        int row = mb * 128 + wm + sm * 16 + q * 4 + r;
        if (row < ne) {
          int col = fb * 64 + wn + sn * 16 + fr;
          float g = accG[sm][sn][r];
          float u = accU[sm][sn][r];
          float h = (g / (1.f + expf(-g))) * u;
          hbuf[(size_t)(base + row) * FDIM + col] = f2bf(h);
        }
      }
}

// ---------------- GEMM2: Y += rw * (H W2^T), 128x128 tile (m97 shape) --------
__global__ __launch_bounds__(256) void k_gemm2(
    const unsigned short* __restrict__ hbuf, const unsigned short* __restrict__ w2b,
    const int* __restrict__ cnt, const int* __restrict__ prefix,
    const int* __restrict__ toks, const float* __restrict__ rwc,
    float* __restrict__ y) {
  int e  = blockIdx.x >> 6;
  int mb = blockIdx.x & 63;
  int ne = cnt[e];
  if (mb * 128 >= ne) return;
  int base = prefix[e];
  int db = blockIdx.y;   // D/128

  __shared__ __align__(16) unsigned short As[128 * BK];
  __shared__ __align__(16) unsigned short Bs[128 * BK];
  __shared__ int ltok[128];
  __shared__ float lrw[128];

  int tid = threadIdx.x;
  if (tid < 128) {
    int i = mb * 128 + tid;
    ltok[tid] = (i < ne) ? toks[base + i] : 0;
    lrw[tid]  = (i < ne) ? rwc[base + i] : 0.f;
  }

  int lane = tid & 63;
  int wv = tid >> 6;
  int r_in_seg = lane >> 2;
  int c16 = (lane & 3) * 8;
  const unsigned short* gsrc[4];
  unsigned short* ldst[4];
#pragma unroll
  for (int i = 0; i < 4; i++) {
    int seg = wv * 4 + i;
    if (seg < 8) {
      int row = seg * 16 + r_in_seg;            // 0..127, contiguous hbuf slots
      gsrc[i] = hbuf + (size_t)(base + mb * 128 + row) * FDIM + c16;
      ldst[i] = (unsigned short*)As + seg * 16 * BK;
    } else {
      int row = (seg - 8) * 16 + r_in_seg;      // 0..127
      gsrc[i] = w2b + ((size_t)e * DDIM + db * 128 + row) * FDIM + c16;
      ldst[i] = (unsigned short*)Bs + (seg - 8) * 16 * BK;
    }
  }

  int fr = lane & 15;
  int q  = lane >> 4;
  int wm = (wv >> 1) * 64;   // wave grid 2x2: 64x64 per wave
  int wn = (wv & 1) * 64;

  f32x4 acc[4][4];
#pragma unroll
  for (int i = 0; i < 4; i++)
#pragma unroll
    for (int j = 0; j < 4; j++) acc[i][j] = (f32x4){0,0,0,0};

  for (int k0 = 0; k0 < FDIM; k0 += BK) {
#pragma unroll
    for (int i = 0; i < 4; i++) GLDS16(gsrc[i] + k0, ldst[i]);
    __syncthreads();

    bf16x8 af[4], bf[4];
#pragma unroll
    for (int sm = 0; sm < 4; sm++)
      af[sm] = *(const bf16x8*)(As + (wm + sm * 16 + fr) * BK + q * 8);
#pragma unroll
    for (int sn = 0; sn < 4; sn++)
      bf[sn] = *(const bf16x8*)(Bs + (wn + sn * 16 + fr) * BK + q * 8);
#pragma unroll
    for (int sm = 0; sm < 4; sm++)
#pragma unroll
      for (int sn = 0; sn < 4; sn++)
        acc[sm][sn] = MFMA16(af[sm], bf[sn], acc[sm][sn]);
    __syncthreads();
  }

#pragma unroll
  for (int sm = 0; sm < 4; sm++)
#pragma unroll
    for (int sn = 0; sn < 4; sn++)
#pragma unroll
      for (int r = 0; r < 4; r++) {
        int lrow = wm + sm * 16 + q * 4 + r;
        int row = mb * 128 + lrow;
        if (row < ne) {
          int tok = ltok[lrow];
          float w = lrw[lrow];
          int col = db * 128 + wn + sn * 16 + fr;
          atomicAdd(&y[(size_t)tok * DDIM + col], acc[sm][sn][r] * w);
        }
      }
}

// ---------------- launch ----------------
// ws layout (bytes), 16B-aligned chunks:
//   0          cnt[8] / 256 fill[8] / 512 prefix[9]
//   1024       topk_e[16384]            (64 KiB)
//   66560      topk_w[16384]            (64 KiB)
//   132096     toks[16384]              (64 KiB)
//   197632     rwc[16384]               (64 KiB)
//   263168     hbuf: 16512 x 2048 bf16  (67.6 MB; +128 pad rows for tile overrun)
//   67896320   w1b bf16                 (67.1 MB)
//   135005184  w3b bf16                 (67.1 MB)
//   202114048  w2b bf16                 (67.1 MB)
//   269222912  xb  bf16                 (33.6 MB)   total ~302.8 MB
extern "C" void kernel_launch(void* const* d_in, const int* in_sizes, int n_in,
                              void* d_out, int out_size, void* d_ws, size_t ws_size,
                              hipStream_t stream) {
  const float* x  = (const float*)d_in[0];
  const float* gw = (const float*)d_in[1];
  const float* w1 = (const float*)d_in[2];
  const float* w3 = (const float*)d_in[3];
  const float* w2 = (const float*)d_in[4];
  float* y = (float*)d_out;

  char* ws = (char*)d_ws;
  int*   cnt    = (int*)(ws + 0);
  int*   fill   = (int*)(ws + 256);
  int*   prefix = (int*)(ws + 512);
  int*   topk_e = (int*)(ws + 1024);
  float* topk_w = (float*)(ws + 66560);
  int*   toks   = (int*)(ws + 132096);
  float* rwc    = (float*)(ws + 197632);
  unsigned short* hbuf = (unsigned short*)(ws + 263168);
  unsigned short* w1b  = (unsigned short*)(ws + 67896320UL);
  unsigned short* w3b  = (unsigned short*)(ws + 135005184UL);
  unsigned short* w2b  = (unsigned short*)(ws + 202114048UL);
  unsigned short* xb   = (unsigned short*)(ws + 269222912UL);

  const long NW = (long)NEXP * FDIM * DDIM;   // 33.55M per weight tensor
  const long NX = (long)T_TOK * DDIM;         // 16.78M

  hipMemsetAsync(ws, 0, 1024, stream);
  hipMemsetAsync(d_out, 0, (size_t)out_size * sizeof(float), stream);

  k_cvt<<<1024, 256, 0, stream>>>(w1, w1b, NW);
  k_cvt<<<1024, 256, 0, stream>>>(w3, w3b, NW);
  k_cvt<<<1024, 256, 0, stream>>>(w2, w2b, NW);
  k_cvt<<<1024, 256, 0, stream>>>(x,  xb,  NX);

  k_router<<<T_TOK / 4, 256, 0, stream>>>(x, gw, cnt, topk_e, topk_w);
  k_scan<<<1, 64, 0, stream>>>(cnt, prefix);
  k_assign<<<T_TOK / 256, 256, 0, stream>>>(topk_e, topk_w, prefix, fill, toks, rwc);

  k_gemm1<<<dim3(NEXP * 64, FDIM / 64), 256, 0, stream>>>(xb, w1b, w3b, cnt, prefix, toks, hbuf);
  k_gemm2<<<dim3(NEXP * 64, DDIM / 128), 256, 0, stream>>>(hbuf, w2b, cnt, prefix, toks, rwc, y);
}